// Round 21
// baseline (178.714 us; speedup 1.0000x reference)
//
#include <hip/hip_runtime.h>
#include <hip/hip_bf16.h>

typedef __bf16 bf16x8 __attribute__((ext_vector_type(8)));
typedef __bf16 bf16x4 __attribute__((ext_vector_type(4)));
typedef float f32x4 __attribute__((ext_vector_type(4)));

#define NEG_INF (-__builtin_inff())

// ---------------------------------------------------------------------------
// ALL f32->bf16 conversions in ONE launch: x (8.4M) + Wq/Wk/Wv -> wqkv + Wo.
// 12582912 elements, 4/thread, grid 12288 x 256.
// ---------------------------------------------------------------------------
__global__ void cvt_all(const float* __restrict__ x,
                        const float* __restrict__ Wq, const float* __restrict__ Wk,
                        const float* __restrict__ Wv, const float* __restrict__ Wo,
                        __bf16* __restrict__ xb, __bf16* __restrict__ wqkv,
                        __bf16* __restrict__ wo_b) {
    int i = (blockIdx.x * blockDim.x + threadIdx.x) * 4;
    const float* src;
    __bf16* dst;
    int off;
    if (i < 8388608) {
        src = x; dst = xb; off = i;
    } else {
        int j = i - 8388608;
        int sel = j >> 20;            // 0..3
        off = j & 1048575;
        src = (sel == 0) ? Wq : (sel == 1) ? Wk : (sel == 2) ? Wv : Wo;
        dst = (sel < 3) ? (wqkv + (size_t)sel * 1048576) : wo_b;
    }
    float4 v = *(const float4*)(src + off);
    bf16x4 o;
    o[0] = (__bf16)v.x; o[1] = (__bf16)v.y; o[2] = (__bf16)v.z; o[3] = (__bf16)v.w;
    *(bf16x4*)(dst + off) = o;
}

// ---------------------------------------------------------------------------
// m97-structure GEMM: 128x128 tile, BK=64, 256 threads (4 waves 2x2),
// SINGLE-buffer linear LDS 32KB, global_load_lds width=16, 2 barriers/K-step.
// MODE 0 uses the L2-supertile block map (r17 win): 8m x 4n chunks per XCD,
// working set A 2MB + B 1MB fits the 4MB per-XCD L2 (FETCH 91->42MB).
// Q scale = 0.125*log2e (exp2-domain softmax downstream; r20 win).
// out[m][n] = sum_k A[m][k]*B[n][k]  (A:[M][K], B:[N][K], bf16).
// MODE 0: bf16 out scattered to QKV layout; V transposed Vt[bh][d][2048].
// MODE 1: f32 out row-major [M][N].
// ---------------------------------------------------------------------------
template <int MODE>
__launch_bounds__(256, 4)
__global__ void gemm_bt(const __bf16* __restrict__ A, const __bf16* __restrict__ Bm,
                        void* __restrict__ Out, int M, int N, int K) {
    __shared__ __align__(1024) char smem[32768];   // As [128][64] | Bs [128][64]
    const int tid = threadIdx.x;
    const int w = tid >> 6, lane = tid & 63;
    const int lr = lane & 15, lg = lane >> 4;
    const int wm0 = (w >> 1) * 64, wn0 = (w & 1) * 64;

    const int nbx = gridDim.x;
    int id = blockIdx.y * nbx + blockIdx.x;
    int m0, n0;
    if (MODE == 0) {
        // grid 1536 = 64 m-rows x 24 n-cols; XCD xcd owns m-rows 8*xcd..8*xcd+7.
        int xcd = id & 7, local = id >> 3;        // local 0..191, dispatched in order
        int chunk = local >> 5, wi = local & 31;
        int mrow = wi >> 2, ncol = (chunk << 2) + (wi & 3);
        m0 = (xcd * 8 + mrow) * 128;
        n0 = ncol * 128;
    } else {
        // bijective XCD swizzle (512 % 8 == 0); per-XCD 8x8 tiles = 4MB, L2-fit
        int q8 = (nbx * gridDim.y) >> 3;
        int vid = (id & 7) * q8 + (id >> 3);
        m0 = (vid / nbx) * 128;
        n0 = (vid % nbx) * 128;
    }

    const char* Ab = (const char*)A;
    const char* Bb = (const char*)Bm;

    f32x4 acc[4][4] = {};

    const int s_row8 = lane >> 3;   // 0..7
    const int s_col16 = lane & 7;   // 0..7

    const int nt = K >> 6;
    for (int t = 0; t < nt; ++t) {
#pragma unroll
        for (int r = 0; r < 4; ++r) {
            int c = w * 4 + r;                       // wave-uniform chunk 0..15
            int row = c * 8 + s_row8;
            const char* srcA = Ab + ((size_t)(m0 + row) * K + t * 64) * 2 + s_col16 * 16;
            const char* srcB = Bb + ((size_t)(n0 + row) * K + t * 64) * 2 + s_col16 * 16;
            __builtin_amdgcn_global_load_lds(
                (const __attribute__((address_space(1))) void*)srcA,
                (__attribute__((address_space(3))) void*)(smem + c * 1024), 16, 0, 0);
            __builtin_amdgcn_global_load_lds(
                (const __attribute__((address_space(1))) void*)srcB,
                (__attribute__((address_space(3))) void*)(smem + 16384 + c * 1024), 16, 0, 0);
        }
        __syncthreads();   // drains vmcnt(0): tile resident

#pragma unroll
        for (int kk = 0; kk < 2; ++kk) {
            bf16x8 af[4], bf[4];
#pragma unroll
            for (int mi = 0; mi < 4; ++mi)
                af[mi] = *(const bf16x8*)(smem + (wm0 + mi * 16 + lr) * 128 + kk * 64 + lg * 16);
#pragma unroll
            for (int ni = 0; ni < 4; ++ni)
                bf[ni] = *(const bf16x8*)(smem + 16384 + (wn0 + ni * 16 + lr) * 128 + kk * 64 + lg * 16);
            __builtin_amdgcn_s_setprio(1);
#pragma unroll
            for (int mi = 0; mi < 4; ++mi)
#pragma unroll
                for (int ni = 0; ni < 4; ++ni)
                    acc[mi][ni] = __builtin_amdgcn_mfma_f32_16x16x32_bf16(
                        af[mi], bf[ni], acc[mi][ni], 0, 0, 0);
            __builtin_amdgcn_s_setprio(0);
        }
        __syncthreads();   // all reads done before next stage overwrites
    }

    // epilogue: D layout col = lane&15 (n), row = (lane>>4)*4 + r (m)
#pragma unroll
    for (int mi = 0; mi < 4; ++mi)
#pragma unroll
        for (int ni = 0; ni < 4; ++ni)
#pragma unroll
            for (int r = 0; r < 4; ++r) {
                int m = m0 + wm0 + mi * 16 + lg * 4 + r;
                int n = n0 + wn0 + ni * 16 + lr;
                float v = acc[mi][ni][r];
                if (MODE == 0) {
                    int proj = n >> 10, nn = n & 1023;
                    int h = nn >> 6, d = nn & 63;
                    int bb = m >> 11, c = m & 2047;
                    if (proj == 2) {
                        // Vt layout: [bh][d][2048]
                        ((__bf16*)Out)[(size_t)2 * 8388608 +
                                       ((size_t)((bb * 16 + h) * 64 + d)) * 2048 + c] = (__bf16)v;
                    } else {
                        // Q scale folds 1/sqrt(64) AND log2(e): exp2-domain softmax
                        float scale = (proj == 0) ? 0.18033688011f : 1.0f;
                        ((__bf16*)Out)[(size_t)proj * 8388608 +
                                       ((size_t)(bb * 16 + h) * 2048 + c) * 64 + d] =
                            (__bf16)(v * scale);
                    }
                } else {
                    ((float*)Out)[(size_t)m * N + n] = v;
                }
            }
}

// ---------------------------------------------------------------------------
// Flash attention (causal), swapped-QK^T, MERGED passes, exp2 softmax (r20),
// R21: T5 s_setprio(1) around the QK^T and PV MFMA clusters (m191: +4-7%
// attn — cross-block phase diversity at 4 blocks/CU lets MFMA-entering
// waves preempt other blocks' staging/VALU waves on the shared SIMD).
// ---------------------------------------------------------------------------
__device__ __forceinline__ unsigned swz(unsigned d) {
    return d ^ (((d >> 7) & 7) << 4);
}

__launch_bounds__(256, 4)
__global__ void attn_fwd(const __bf16* __restrict__ Q, const __bf16* __restrict__ K,
                         const __bf16* __restrict__ Vt, __bf16* __restrict__ Aout) {
    __shared__ char smem[40960];   // K dbuf 2x8KB | Vt dbuf 2x8KB | P 4x2KB
    const int id = blockIdx.x;
    const int vid = (id & 7) * 128 + (id >> 3);   // bijective XCD swizzle
    const int bh = vid >> 4, pr = vid & 15;
    const int w = threadIdx.x >> 6, lane = threadIdx.x & 63;
    const int lr = lane & 15, lg = lane >> 4;
    const char* Kb  = (const char*)(K  + (size_t)bh * 2048 * 64);
    const char* Vtb = (const char*)(Vt + (size_t)bh * 64 * 2048);
    const __bf16* Qb = Q + (size_t)bh * 2048 * 64;
    const int b = bh >> 4, h = bh & 15;
    char* Pb = smem + 32768 + w * 2048;

    const int qta = 31 - pr, qtb = pr;            // qta >= 16 > qtb
    const int q0a = qta * 64 + w * 16, q0b = qtb * 64 + w * 16;

    bf16x8 qfa[2], qfb[2];
#pragma unroll
    for (int kk = 0; kk < 2; ++kk) {
        qfa[kk] = *(const bf16x8*)&Qb[(size_t)(q0a + lr) * 64 + kk * 32 + lg * 8];
        qfb[kk] = *(const bf16x8*)&Qb[(size_t)(q0b + lr) * 64 + kk * 32 + lg * 8];
    }

    f32x4 oa[4] = {}, ob[4] = {};
    float ma = NEG_INF, la = 0.f, mb = NEG_INF, lb = 0.f;

    // prologue: stage tile 0 -> buf 0
    {
        char* kd = smem;
        char* vd = smem + 16384;
#pragma unroll
        for (int i = 0; i < 2; ++i) {
            unsigned c = (unsigned)(w * 2 + i);
            unsigned d = c * 1024 + (unsigned)lane * 16;
            unsigned bs = swz(d);
            __builtin_amdgcn_global_load_lds(
                (const __attribute__((address_space(1))) void*)(Kb + bs),
                (__attribute__((address_space(3))) void*)(kd + c * 1024), 16, 0, 0);
            unsigned row = bs >> 7, colb = bs & 127;
            __builtin_amdgcn_global_load_lds(
                (const __attribute__((address_space(1))) void*)(Vtb + (size_t)row * 4096 + colb),
                (__attribute__((address_space(3))) void*)(vd + c * 1024), 16, 0, 0);
        }
    }

    const int nt = qta + 1;
    for (int t = 0; t < nt; ++t) {
        __syncthreads();   // implicit vmcnt(0)+lgkmcnt(0): tile t resident, old reads done
        if (t + 1 < nt) {  // prefetch t+1 while computing t
            char* kd = smem + ((t + 1) & 1) * 8192;
            char* vd = smem + 16384 + ((t + 1) & 1) * 8192;
#pragma unroll
            for (int i = 0; i < 2; ++i) {
                unsigned c = (unsigned)(w * 2 + i);
                unsigned d = c * 1024 + (unsigned)lane * 16;
                unsigned bs = swz(d);
                __builtin_amdgcn_global_load_lds(
                    (const __attribute__((address_space(1))) void*)(Kb + (size_t)(t + 1) * 8192 + bs),
                    (__attribute__((address_space(3))) void*)(kd + c * 1024), 16, 0, 0);
                unsigned row = bs >> 7, colb = bs & 127;
                __builtin_amdgcn_global_load_lds(
                    (const __attribute__((address_space(1))) void*)(Vtb + (size_t)row * 4096 +
                                                                   (size_t)(t + 1) * 128 + colb),
                    (__attribute__((address_space(3))) void*)(vd + c * 1024), 16, 0, 0);
            }
        }
        const char* Ks = smem + (t & 1) * 8192;
        const char* Vs = smem + 16384 + (t & 1) * 8192;
        const int k0 = t * 64;

        // one q-tile's full per-tile body (QK^T -> online softmax -> PV)
        auto process = [&](const bf16x8 (&qf)[2], int q0, bool diag,
                           f32x4 (&o)[4], float& m, float& l) {
            f32x4 s[4] = {};
#pragma unroll
            for (int kk = 0; kk < 2; ++kk) {
                bf16x8 kf[4];
#pragma unroll
                for (int sub = 0; sub < 4; ++sub)
                    kf[sub] = *(const bf16x8*)(Ks + swz((unsigned)((sub * 16 + lr) * 128 + kk * 64 + lg * 16)));
                __builtin_amdgcn_s_setprio(1);
#pragma unroll
                for (int sub = 0; sub < 4; ++sub)
                    s[sub] = __builtin_amdgcn_mfma_f32_16x16x32_bf16(kf[sub], qf[kk], s[sub], 0, 0, 0);
                __builtin_amdgcn_s_setprio(0);
            }
            if (diag) {
#pragma unroll
                for (int sub = 0; sub < 4; ++sub)
#pragma unroll
                    for (int r = 0; r < 4; ++r)
                        if (k0 + sub * 16 + lg * 4 + r > q0 + lr) s[sub][r] = NEG_INF;
            }
            float mloc = NEG_INF;
#pragma unroll
            for (int sub = 0; sub < 4; ++sub)
#pragma unroll
                for (int r = 0; r < 4; ++r) mloc = fmaxf(mloc, s[sub][r]);
            mloc = fmaxf(mloc, __shfl_xor(mloc, 16));
            mloc = fmaxf(mloc, __shfl_xor(mloc, 32));
            float mnew = fmaxf(m, mloc);
            float alpha = __builtin_amdgcn_exp2f(m - mnew);
            float rs = 0.f;
#pragma unroll
            for (int sub = 0; sub < 4; ++sub)
#pragma unroll
                for (int r = 0; r < 4; ++r) {
                    float p = __builtin_amdgcn_exp2f(s[sub][r] - mnew);
                    s[sub][r] = p;
                    rs += p;
                }
            rs += __shfl_xor(rs, 16);
            rs += __shfl_xor(rs, 32);
            l = l * alpha + rs;
            m = mnew;
#pragma unroll
            for (int ni = 0; ni < 4; ++ni) o[ni] *= alpha;

#pragma unroll
            for (int sub = 0; sub < 4; ++sub) {
                bf16x4 pk;
#pragma unroll
                for (int r = 0; r < 4; ++r) pk[r] = (__bf16)s[sub][r];
                *(bf16x4*)(Pb + swz((unsigned)(lr * 128 + sub * 32 + lg * 8))) = pk;
            }
            bf16x8 pfr[2];
#pragma unroll
            for (int kk = 0; kk < 2; ++kk)
                pfr[kk] = *(const bf16x8*)(Pb + swz((unsigned)(lr * 128 + kk * 64 + lg * 16)));

#pragma unroll
            for (int kk = 0; kk < 2; ++kk) {
                bf16x8 vf[4];
#pragma unroll
                for (int ni = 0; ni < 4; ++ni)
                    vf[ni] = *(const bf16x8*)(Vs + swz((unsigned)((ni * 16 + lr) * 128 + kk * 64 + lg * 16)));
                __builtin_amdgcn_s_setprio(1);
#pragma unroll
                for (int ni = 0; ni < 4; ++ni)
                    o[ni] = __builtin_amdgcn_mfma_f32_16x16x32_bf16(vf[ni], pfr[kk], o[ni], 0, 0, 0);
                __builtin_amdgcn_s_setprio(0);
            }
        };

        process(qfa, q0a, t == qta, oa, ma, la);
        if (t <= qtb) process(qfb, q0b, t == qtb, ob, mb, lb);
    }

    // epilogue: Aout[b][c][h*64 + ni*16 + lg*4], vectorized 8B stores
    float ra = 1.0f / la, rb = 1.0f / lb;
#pragma unroll
    for (int ni = 0; ni < 4; ++ni) {
        bf16x4 va, vb;
#pragma unroll
        for (int r = 0; r < 4; ++r) {
            va[r] = (__bf16)(oa[ni][r] * ra);
            vb[r] = (__bf16)(ob[ni][r] * rb);
        }
        *(bf16x4*)&Aout[((size_t)b * 2048 + q0a + lr) * 1024 + h * 64 + ni * 16 + lg * 4] = va;
        *(bf16x4*)&Aout[((size_t)b * 2048 + q0b + lr) * 1024 + h * 64 + ni * 16 + lg * 4] = vb;
    }
}

// ---------------------------------------------------------------------------
// launch
// ---------------------------------------------------------------------------
extern "C" void kernel_launch(void* const* d_in, const int* in_sizes, int n_in,
                              void* d_out, int out_size, void* d_ws, size_t ws_size,
                              hipStream_t stream) {
    const float* x  = (const float*)d_in[0];
    const float* Wk = (const float*)d_in[1];   // dict order: x, Wk, Wq, Wv, Wo
    const float* Wq = (const float*)d_in[2];
    const float* Wv = (const float*)d_in[3];
    const float* Wo = (const float*)d_in[4];

    char* ws = (char*)d_ws;
    __bf16* xb   = (__bf16*)(ws);                 // [8192][1024]        16 MB
    __bf16* wqkv = (__bf16*)(ws + 16777216);      // [3072][1024]         6 MB
    __bf16* wo_b = (__bf16*)(ws + 23068672);      // [1024][1024]         2 MB
    __bf16* qkv  = (__bf16*)(ws + 25165824);      // Q,K: [64][2048][64]; Vt: [64][64][2048]
    __bf16* aout = (__bf16*)(ws + 75497472);      // [8192][1024]        16 MB
    float* out = (float*)d_out;

    cvt_all<<<12288, 256, 0, stream>>>(x, Wq, Wk, Wv, Wo, xb, wqkv, wo_b);

    gemm_bt<0><<<dim3(24, 64), 256, 0, stream>>>(xb, wqkv, qkv, 8192, 3072, 1024);
    attn_fwd<<<dim3(1024), 256, 0, stream>>>(qkv, qkv + 8388608, qkv + 16777216, aout);
    gemm_bt<1><<<dim3(8, 64), 256, 0, stream>>>(aout, wo_b, out, 8192, 1024, 1024);
}

// Round 22
// 178.091 us; speedup vs baseline: 1.0035x; 1.0035x over previous
//
#include <hip/hip_runtime.h>
#include <hip/hip_bf16.h>

typedef __bf16 bf16x8 __attribute__((ext_vector_type(8)));
typedef __bf16 bf16x4 __attribute__((ext_vector_type(4)));
typedef float f32x4 __attribute__((ext_vector_type(4)));

#define NEG_INF (-__builtin_inff())

// ---------------------------------------------------------------------------
// ALL f32->bf16 conversions in ONE launch: x (8.4M) + Wq/Wk/Wv -> wqkv + Wo.
// 12582912 elements, 4/thread, grid 12288 x 256.
// ---------------------------------------------------------------------------
__global__ void cvt_all(const float* __restrict__ x,
                        const float* __restrict__ Wq, const float* __restrict__ Wk,
                        const float* __restrict__ Wv, const float* __restrict__ Wo,
                        __bf16* __restrict__ xb, __bf16* __restrict__ wqkv,
                        __bf16* __restrict__ wo_b) {
    int i = (blockIdx.x * blockDim.x + threadIdx.x) * 4;
    const float* src;
    __bf16* dst;
    int off;
    if (i < 8388608) {
        src = x; dst = xb; off = i;
    } else {
        int j = i - 8388608;
        int sel = j >> 20;            // 0..3
        off = j & 1048575;
        src = (sel == 0) ? Wq : (sel == 1) ? Wk : (sel == 2) ? Wv : Wo;
        dst = (sel < 3) ? (wqkv + (size_t)sel * 1048576) : wo_b;
    }
    float4 v = *(const float4*)(src + off);
    bf16x4 o;
    o[0] = (__bf16)v.x; o[1] = (__bf16)v.y; o[2] = (__bf16)v.z; o[3] = (__bf16)v.w;
    *(bf16x4*)(dst + off) = o;
}

// ---------------------------------------------------------------------------
// m97-structure GEMM: 128x128 tile, BK=64, 256 threads (4 waves 2x2),
// SINGLE-buffer linear LDS 32KB, global_load_lds width=16, 2 barriers/K-step.
// MODE 0 uses the L2-supertile block map (r17 win): 8m x 4n chunks per XCD,
// working set A 2MB + B 1MB fits the 4MB per-XCD L2 (FETCH 91->42MB).
// Q scale = 0.125*log2e (exp2-domain softmax downstream; r20 win).
// out[m][n] = sum_k A[m][k]*B[n][k]  (A:[M][K], B:[N][K], bf16).
// MODE 0: bf16 out scattered to QKV layout; V transposed Vt[bh][d][2048].
// MODE 1: f32 out row-major [M][N].
// ---------------------------------------------------------------------------
template <int MODE>
__launch_bounds__(256, 4)
__global__ void gemm_bt(const __bf16* __restrict__ A, const __bf16* __restrict__ Bm,
                        void* __restrict__ Out, int M, int N, int K) {
    __shared__ __align__(1024) char smem[32768];   // As [128][64] | Bs [128][64]
    const int tid = threadIdx.x;
    const int w = tid >> 6, lane = tid & 63;
    const int lr = lane & 15, lg = lane >> 4;
    const int wm0 = (w >> 1) * 64, wn0 = (w & 1) * 64;

    const int nbx = gridDim.x;
    int id = blockIdx.y * nbx + blockIdx.x;
    int m0, n0;
    if (MODE == 0) {
        // grid 1536 = 64 m-rows x 24 n-cols; XCD xcd owns m-rows 8*xcd..8*xcd+7.
        int xcd = id & 7, local = id >> 3;        // local 0..191, dispatched in order
        int chunk = local >> 5, wi = local & 31;
        int mrow = wi >> 2, ncol = (chunk << 2) + (wi & 3);
        m0 = (xcd * 8 + mrow) * 128;
        n0 = ncol * 128;
    } else {
        // bijective XCD swizzle (512 % 8 == 0); per-XCD 8x8 tiles = 4MB, L2-fit
        int q8 = (nbx * gridDim.y) >> 3;
        int vid = (id & 7) * q8 + (id >> 3);
        m0 = (vid / nbx) * 128;
        n0 = (vid % nbx) * 128;
    }

    const char* Ab = (const char*)A;
    const char* Bb = (const char*)Bm;

    f32x4 acc[4][4] = {};

    const int s_row8 = lane >> 3;   // 0..7
    const int s_col16 = lane & 7;   // 0..7

    const int nt = K >> 6;
    for (int t = 0; t < nt; ++t) {
#pragma unroll
        for (int r = 0; r < 4; ++r) {
            int c = w * 4 + r;                       // wave-uniform chunk 0..15
            int row = c * 8 + s_row8;
            const char* srcA = Ab + ((size_t)(m0 + row) * K + t * 64) * 2 + s_col16 * 16;
            const char* srcB = Bb + ((size_t)(n0 + row) * K + t * 64) * 2 + s_col16 * 16;
            __builtin_amdgcn_global_load_lds(
                (const __attribute__((address_space(1))) void*)srcA,
                (__attribute__((address_space(3))) void*)(smem + c * 1024), 16, 0, 0);
            __builtin_amdgcn_global_load_lds(
                (const __attribute__((address_space(1))) void*)srcB,
                (__attribute__((address_space(3))) void*)(smem + 16384 + c * 1024), 16, 0, 0);
        }
        __syncthreads();   // drains vmcnt(0): tile resident

#pragma unroll
        for (int kk = 0; kk < 2; ++kk) {
            bf16x8 af[4], bf[4];
#pragma unroll
            for (int mi = 0; mi < 4; ++mi)
                af[mi] = *(const bf16x8*)(smem + (wm0 + mi * 16 + lr) * 128 + kk * 64 + lg * 16);
#pragma unroll
            for (int ni = 0; ni < 4; ++ni)
                bf[ni] = *(const bf16x8*)(smem + 16384 + (wn0 + ni * 16 + lr) * 128 + kk * 64 + lg * 16);
            __builtin_amdgcn_s_setprio(1);
#pragma unroll
            for (int mi = 0; mi < 4; ++mi)
#pragma unroll
                for (int ni = 0; ni < 4; ++ni)
                    acc[mi][ni] = __builtin_amdgcn_mfma_f32_16x16x32_bf16(
                        af[mi], bf[ni], acc[mi][ni], 0, 0, 0);
            __builtin_amdgcn_s_setprio(0);
        }
        __syncthreads();   // all reads done before next stage overwrites
    }

    // epilogue: D layout col = lane&15 (n), row = (lane>>4)*4 + r (m)
#pragma unroll
    for (int mi = 0; mi < 4; ++mi)
#pragma unroll
        for (int ni = 0; ni < 4; ++ni)
#pragma unroll
            for (int r = 0; r < 4; ++r) {
                int m = m0 + wm0 + mi * 16 + lg * 4 + r;
                int n = n0 + wn0 + ni * 16 + lr;
                float v = acc[mi][ni][r];
                if (MODE == 0) {
                    int proj = n >> 10, nn = n & 1023;
                    int h = nn >> 6, d = nn & 63;
                    int bb = m >> 11, c = m & 2047;
                    if (proj == 2) {
                        // Vt layout: [bh][d][2048]
                        ((__bf16*)Out)[(size_t)2 * 8388608 +
                                       ((size_t)((bb * 16 + h) * 64 + d)) * 2048 + c] = (__bf16)v;
                    } else {
                        // Q scale folds 1/sqrt(64) AND log2(e): exp2-domain softmax
                        float scale = (proj == 0) ? 0.18033688011f : 1.0f;
                        ((__bf16*)Out)[(size_t)proj * 8388608 +
                                       ((size_t)(bb * 16 + h) * 2048 + c) * 64 + d] =
                            (__bf16)(v * scale);
                    }
                } else {
                    ((float*)Out)[(size_t)m * N + n] = v;
                }
            }
}

// ---------------------------------------------------------------------------
// Flash attention (causal), swapped-QK^T, MERGED passes, exp2-domain softmax
// (r20-proven final form; r21's attn-setprio was neutral and is reverted).
// ---------------------------------------------------------------------------
__device__ __forceinline__ unsigned swz(unsigned d) {
    return d ^ (((d >> 7) & 7) << 4);
}

__launch_bounds__(256, 4)
__global__ void attn_fwd(const __bf16* __restrict__ Q, const __bf16* __restrict__ K,
                         const __bf16* __restrict__ Vt, __bf16* __restrict__ Aout) {
    __shared__ char smem[40960];   // K dbuf 2x8KB | Vt dbuf 2x8KB | P 4x2KB
    const int id = blockIdx.x;
    const int vid = (id & 7) * 128 + (id >> 3);   // bijective XCD swizzle
    const int bh = vid >> 4, pr = vid & 15;
    const int w = threadIdx.x >> 6, lane = threadIdx.x & 63;
    const int lr = lane & 15, lg = lane >> 4;
    const char* Kb  = (const char*)(K  + (size_t)bh * 2048 * 64);
    const char* Vtb = (const char*)(Vt + (size_t)bh * 64 * 2048);
    const __bf16* Qb = Q + (size_t)bh * 2048 * 64;
    const int b = bh >> 4, h = bh & 15;
    char* Pb = smem + 32768 + w * 2048;

    const int qta = 31 - pr, qtb = pr;            // qta >= 16 > qtb
    const int q0a = qta * 64 + w * 16, q0b = qtb * 64 + w * 16;

    bf16x8 qfa[2], qfb[2];
#pragma unroll
    for (int kk = 0; kk < 2; ++kk) {
        qfa[kk] = *(const bf16x8*)&Qb[(size_t)(q0a + lr) * 64 + kk * 32 + lg * 8];
        qfb[kk] = *(const bf16x8*)&Qb[(size_t)(q0b + lr) * 64 + kk * 32 + lg * 8];
    }

    f32x4 oa[4] = {}, ob[4] = {};
    float ma = NEG_INF, la = 0.f, mb = NEG_INF, lb = 0.f;

    // prologue: stage tile 0 -> buf 0
    {
        char* kd = smem;
        char* vd = smem + 16384;
#pragma unroll
        for (int i = 0; i < 2; ++i) {
            unsigned c = (unsigned)(w * 2 + i);
            unsigned d = c * 1024 + (unsigned)lane * 16;
            unsigned bs = swz(d);
            __builtin_amdgcn_global_load_lds(
                (const __attribute__((address_space(1))) void*)(Kb + bs),
                (__attribute__((address_space(3))) void*)(kd + c * 1024), 16, 0, 0);
            unsigned row = bs >> 7, colb = bs & 127;
            __builtin_amdgcn_global_load_lds(
                (const __attribute__((address_space(1))) void*)(Vtb + (size_t)row * 4096 + colb),
                (__attribute__((address_space(3))) void*)(vd + c * 1024), 16, 0, 0);
        }
    }

    const int nt = qta + 1;
    for (int t = 0; t < nt; ++t) {
        __syncthreads();   // implicit vmcnt(0)+lgkmcnt(0): tile t resident, old reads done
        if (t + 1 < nt) {  // prefetch t+1 while computing t
            char* kd = smem + ((t + 1) & 1) * 8192;
            char* vd = smem + 16384 + ((t + 1) & 1) * 8192;
#pragma unroll
            for (int i = 0; i < 2; ++i) {
                unsigned c = (unsigned)(w * 2 + i);
                unsigned d = c * 1024 + (unsigned)lane * 16;
                unsigned bs = swz(d);
                __builtin_amdgcn_global_load_lds(
                    (const __attribute__((address_space(1))) void*)(Kb + (size_t)(t + 1) * 8192 + bs),
                    (__attribute__((address_space(3))) void*)(kd + c * 1024), 16, 0, 0);
                unsigned row = bs >> 7, colb = bs & 127;
                __builtin_amdgcn_global_load_lds(
                    (const __attribute__((address_space(1))) void*)(Vtb + (size_t)row * 4096 +
                                                                   (size_t)(t + 1) * 128 + colb),
                    (__attribute__((address_space(3))) void*)(vd + c * 1024), 16, 0, 0);
            }
        }
        const char* Ks = smem + (t & 1) * 8192;
        const char* Vs = smem + 16384 + (t & 1) * 8192;
        const int k0 = t * 64;

        // one q-tile's full per-tile body (QK^T -> online softmax -> PV)
        auto process = [&](const bf16x8 (&qf)[2], int q0, bool diag,
                           f32x4 (&o)[4], float& m, float& l) {
            f32x4 s[4] = {};
#pragma unroll
            for (int kk = 0; kk < 2; ++kk)
#pragma unroll
                for (int sub = 0; sub < 4; ++sub) {
                    bf16x8 kf = *(const bf16x8*)(Ks + swz((unsigned)((sub * 16 + lr) * 128 + kk * 64 + lg * 16)));
                    s[sub] = __builtin_amdgcn_mfma_f32_16x16x32_bf16(kf, qf[kk], s[sub], 0, 0, 0);
                }
            if (diag) {
#pragma unroll
                for (int sub = 0; sub < 4; ++sub)
#pragma unroll
                    for (int r = 0; r < 4; ++r)
                        if (k0 + sub * 16 + lg * 4 + r > q0 + lr) s[sub][r] = NEG_INF;
            }
            float mloc = NEG_INF;
#pragma unroll
            for (int sub = 0; sub < 4; ++sub)
#pragma unroll
                for (int r = 0; r < 4; ++r) mloc = fmaxf(mloc, s[sub][r]);
            mloc = fmaxf(mloc, __shfl_xor(mloc, 16));
            mloc = fmaxf(mloc, __shfl_xor(mloc, 32));
            float mnew = fmaxf(m, mloc);
            float alpha = __builtin_amdgcn_exp2f(m - mnew);
            float rs = 0.f;
#pragma unroll
            for (int sub = 0; sub < 4; ++sub)
#pragma unroll
                for (int r = 0; r < 4; ++r) {
                    float p = __builtin_amdgcn_exp2f(s[sub][r] - mnew);
                    s[sub][r] = p;
                    rs += p;
                }
            rs += __shfl_xor(rs, 16);
            rs += __shfl_xor(rs, 32);
            l = l * alpha + rs;
            m = mnew;
#pragma unroll
            for (int ni = 0; ni < 4; ++ni) o[ni] *= alpha;

#pragma unroll
            for (int sub = 0; sub < 4; ++sub) {
                bf16x4 pk;
#pragma unroll
                for (int r = 0; r < 4; ++r) pk[r] = (__bf16)s[sub][r];
                *(bf16x4*)(Pb + swz((unsigned)(lr * 128 + sub * 32 + lg * 8))) = pk;
            }
            bf16x8 pfr[2];
#pragma unroll
            for (int kk = 0; kk < 2; ++kk)
                pfr[kk] = *(const bf16x8*)(Pb + swz((unsigned)(lr * 128 + kk * 64 + lg * 16)));

#pragma unroll
            for (int kk = 0; kk < 2; ++kk)
#pragma unroll
                for (int ni = 0; ni < 4; ++ni) {
                    bf16x8 vf = *(const bf16x8*)(Vs + swz((unsigned)((ni * 16 + lr) * 128 + kk * 64 + lg * 16)));
                    o[ni] = __builtin_amdgcn_mfma_f32_16x16x32_bf16(vf, pfr[kk], o[ni], 0, 0, 0);
                }
        };

        process(qfa, q0a, t == qta, oa, ma, la);
        if (t <= qtb) process(qfb, q0b, t == qtb, ob, mb, lb);
    }

    // epilogue: Aout[b][c][h*64 + ni*16 + lg*4], vectorized 8B stores
    float ra = 1.0f / la, rb = 1.0f / lb;
#pragma unroll
    for (int ni = 0; ni < 4; ++ni) {
        bf16x4 va, vb;
#pragma unroll
        for (int r = 0; r < 4; ++r) {
            va[r] = (__bf16)(oa[ni][r] * ra);
            vb[r] = (__bf16)(ob[ni][r] * rb);
        }
        *(bf16x4*)&Aout[((size_t)b * 2048 + q0a + lr) * 1024 + h * 64 + ni * 16 + lg * 4] = va;
        *(bf16x4*)&Aout[((size_t)b * 2048 + q0b + lr) * 1024 + h * 64 + ni * 16 + lg * 4] = vb;
    }
}

// ---------------------------------------------------------------------------
// launch
// ---------------------------------------------------------------------------
extern "C" void kernel_launch(void* const* d_in, const int* in_sizes, int n_in,
                              void* d_out, int out_size, void* d_ws, size_t ws_size,
                              hipStream_t stream) {
    const float* x  = (const float*)d_in[0];
    const float* Wk = (const float*)d_in[1];   // dict order: x, Wk, Wq, Wv, Wo
    const float* Wq = (const float*)d_in[2];
    const float* Wv = (const float*)d_in[3];
    const float* Wo = (const float*)d_in[4];

    char* ws = (char*)d_ws;
    __bf16* xb   = (__bf16*)(ws);                 // [8192][1024]        16 MB
    __bf16* wqkv = (__bf16*)(ws + 16777216);      // [3072][1024]         6 MB
    __bf16* wo_b = (__bf16*)(ws + 23068672);      // [1024][1024]         2 MB
    __bf16* qkv  = (__bf16*)(ws + 25165824);      // Q,K: [64][2048][64]; Vt: [64][64][2048]
    __bf16* aout = (__bf16*)(ws + 75497472);      // [8192][1024]        16 MB
    float* out = (float*)d_out;

    cvt_all<<<12288, 256, 0, stream>>>(x, Wq, Wk, Wv, Wo, xb, wqkv, wo_b);

    gemm_bt<0><<<dim3(24, 64), 256, 0, stream>>>(xb, wqkv, qkv, 8192, 3072, 1024);
    attn_fwd<<<dim3(1024), 256, 0, stream>>>(qkv, qkv + 8388608, qkv + 16777216, aout);
    gemm_bt<1><<<dim3(8, 64), 256, 0, stream>>>(aout, wo_b, out, 8192, 1024, 1024);
}